// Round 4
// baseline (224.493 us; speedup 1.0000x reference)
//
#include <hip/hip_runtime.h>
#include <math.h>

#define DIMX 128
#define HIDX 256
#define NBX 2048
#define NTOTX 32768
#define NMAXX 32
#define VMID 192
#define SMID 128
#define DMID 192
#define KTAB 256

#define EROWS 32
#define PITCH 34   // even: float2-aligned broadcast reads; writes 4-way (negligible)
#define ITILE 32
#define DPITCH 34

__device__ __forceinline__ float mishf(float v) {
    // exact identity: tanh(log1p(e^v)) = (u^2+2u)/(u^2+2u+2), u=e^v
    if (v > 20.0f) return v;          // tanh(softplus(v)) == 1.0f in fp32
    float u = expf(v);
    float t = u * (u + 2.0f);
    return v * (t / (t + 2.0f));
}

// fused prep: mag dot, key table, segment bounds, wcount reset, output zero
__global__ void k_prep(const float* __restrict__ x, const float* __restrict__ rw,
                       const float* __restrict__ rb, const int* __restrict__ batch,
                       float* __restrict__ mag, int* __restrict__ segs,
                       int* __restrict__ segn, float* __restrict__ ct,
                       float* __restrict__ st, int* __restrict__ wcount,
                       float4* __restrict__ xrz) {
    int blk = blockIdx.x, tid = threadIdx.x;
    if (blk < 8192) {                       // mag: 4 rows/block, 1 wave/row
        int gid = blk * 256 + tid;
        int row = gid >> 6, lane = gid & 63;
        const float* xr = x + (size_t)row * DIMX;
        float s = xr[lane] * rw[lane] + xr[lane + 64] * rw[lane + 64];
#pragma unroll
        for (int off = 32; off; off >>= 1) s += __shfl_down(s, off, 64);
        if (lane == 0) mag[row] = s + rb[0];
    } else if (blk < 8448) {                // key table, k = blk-8192
        int k = blk - 8192;
        float t = (float)tid * (1.0f / 255.0f);
        float th = (t * (float)k) * 8.0f;
        float sv, cv;
        sincosf(th, &sv, &cv);
        ct[k * HIDX + tid] = cv;
        st[k * HIDX + tid] = sv;
    } else if (blk == 8448) {               // segment bounds + wcount reset
        if (tid == 0) wcount[0] = 0;
        for (int b = tid; b < NBX; b += 256) {
            int lo = 0, hi = NTOTX;
            while (lo < hi) { int m = (lo + hi) >> 1; if (batch[m] < b) lo = m + 1; else hi = m; }
            int stt = lo;
            hi = NTOTX;
            while (lo < hi) { int m = (lo + hi) >> 1; if (batch[m] <= b) lo = m + 1; else hi = m; }
            segs[b] = stt; segn[b] = lo - stt;
        }
    } else {                                // zero out_xr: 2048 blocks x 1024 f4
        int base = (blk - 8449) * 1024 + tid;
#pragma unroll
        for (int q = 0; q < 4; q++)
            xrz[base + q * 256] = make_float4(0.f, 0.f, 0.f, 0.f);
    }
}

// stable rank within segment -> order[]
__global__ void k_rank(const int* __restrict__ batch, const float* __restrict__ mag,
                       const int* __restrict__ segs, const int* __restrict__ segn,
                       int* __restrict__ order) {
    int i = blockIdx.x * blockDim.x + threadIdx.x;
    if (i >= NTOTX) return;
    int b = batch[i];
    int s = segs[b], e = s + segn[b];
    float mi = mag[i];
    int r = 0;
    for (int j = s; j < e; j++) {
        float mj = mag[j];
        r += (mj < mi) || (mj == mi && j < i);
    }
    order[s + r] = i;
}

// fused encoder: h = mish(LN(x@w1+b1))@w2 + b2 ; 32 rows/block, 256 thr
// distance-2 software-pipelined weight + LDS-fragment prefetch
__global__ __launch_bounds__(256, 4) void k_enc(const float* __restrict__ x,
    const float* __restrict__ w1, const float* __restrict__ b1,
    const float* __restrict__ g1, const float* __restrict__ be1,
    const float* __restrict__ w2, const float* __restrict__ b2,
    float* __restrict__ h) {
    __shared__ __align__(16) float sT[VMID * PITCH];  // reused: x^T then act^T
    int tid = threadIdx.x;
    int rowbase = blockIdx.x * EROWS;

    // stage x^T: coalesced float4 reads, scattered b32 writes (one-time)
#pragma unroll
    for (int it = 0; it < 4; it++) {
        int idx = it * 256 + tid;
        int r = idx >> 5, kq = idx & 31;
        float4 v = ((const float4*)x)[(size_t)(rowbase + r) * 32 + kq];
        sT[(4 * kq + 0) * PITCH + r] = v.x;
        sT[(4 * kq + 1) * PITCH + r] = v.y;
        sT[(4 * kq + 2) * PITCH + r] = v.z;
        sT[(4 * kq + 3) * PITCH + r] = v.w;
    }
    __syncthreads();

    int c = tid & 63;      // col base (lane)
    int rg = tid >> 6;     // row group of 8
    int r0 = rg * 8;

    // ---- GEMM1: 24 FMA per 3 weight loads, dist-2 pipeline ----
    float a0[8], a1[8], a2[8];
#pragma unroll
    for (int i = 0; i < 8; i++) { a0[i] = 0.f; a1[i] = 0.f; a2[i] = 0.f; }
    const float* w1p = w1 + c;
    float waA = w1p[0], wbA = w1p[64], wcA = w1p[128];
    float waB = w1p[VMID], wbB = w1p[VMID + 64], wcB = w1p[VMID + 128];
    float2 xA0, xA1, xA2, xA3, xB0, xB1, xB2, xB3;
    { const float2* p = (const float2*)&sT[r0];           xA0 = p[0]; xA1 = p[1]; xA2 = p[2]; xA3 = p[3]; }
    { const float2* p = (const float2*)&sT[PITCH + r0];   xB0 = p[0]; xB1 = p[1]; xB2 = p[2]; xB3 = p[3]; }
#pragma unroll 2
    for (int k = 0; k < DIMX; k += 2) {
        int kp = (k + 2 < DIMX) ? (k + 2) : k;
        float nwaA = w1p[kp * VMID],       nwbA = w1p[kp * VMID + 64],       nwcA = w1p[kp * VMID + 128];
        float nwaB = w1p[(kp + 1) * VMID], nwbB = w1p[(kp + 1) * VMID + 64], nwcB = w1p[(kp + 1) * VMID + 128];
        const float2* npA = (const float2*)&sT[kp * PITCH + r0];
        const float2* npB = (const float2*)&sT[(kp + 1) * PITCH + r0];
        float2 nA0 = npA[0], nA1 = npA[1], nA2 = npA[2], nA3 = npA[3];
        float2 nB0 = npB[0], nB1 = npB[1], nB2 = npB[2], nB3 = npB[3];
        float xv[8];
        xv[0] = xA0.x; xv[1] = xA0.y; xv[2] = xA1.x; xv[3] = xA1.y;
        xv[4] = xA2.x; xv[5] = xA2.y; xv[6] = xA3.x; xv[7] = xA3.y;
#pragma unroll
        for (int i = 0; i < 8; i++) {
            a0[i] += waA * xv[i]; a1[i] += wbA * xv[i]; a2[i] += wcA * xv[i];
        }
        xv[0] = xB0.x; xv[1] = xB0.y; xv[2] = xB1.x; xv[3] = xB1.y;
        xv[4] = xB2.x; xv[5] = xB2.y; xv[6] = xB3.x; xv[7] = xB3.y;
#pragma unroll
        for (int i = 0; i < 8; i++) {
            a0[i] += waB * xv[i]; a1[i] += wbB * xv[i]; a2[i] += wcB * xv[i];
        }
        waA = nwaA; wbA = nwbA; wcA = nwcA; waB = nwaB; wbB = nwbB; wcB = nwcB;
        xA0 = nA0; xA1 = nA1; xA2 = nA2; xA3 = nA3;
        xB0 = nB0; xB1 = nB1; xB2 = nB2; xB3 = nB3;
    }

    // ---- LayerNorm + mish (registers + shuffles only) ----
    float b1a = b1[c], b1b = b1[c + 64], b1c = b1[c + 128];
    float g1a = g1[c], g1b = g1[c + 64], g1c = g1[c + 128];
    float e1a = be1[c], e1b = be1[c + 64], e1c = be1[c + 128];
#pragma unroll
    for (int i = 0; i < 8; i++) {
        float v0 = a0[i] + b1a, v1 = a1[i] + b1b, v2 = a2[i] + b1c;
        float s = v0 + v1 + v2;
#pragma unroll
        for (int off = 32; off; off >>= 1) s += __shfl_xor(s, off, 64);
        float mean = s / 192.0f;
        float d0 = v0 - mean, d1 = v1 - mean, d2 = v2 - mean;
        float q = d0 * d0 + d1 * d1 + d2 * d2;
#pragma unroll
        for (int off = 32; off; off >>= 1) q += __shfl_xor(q, off, 64);
        float inv = 1.0f / sqrtf(q / 192.0f + 1e-5f);
        a0[i] = mishf(d0 * inv * g1a + e1a);
        a1[i] = mishf(d1 * inv * g1b + e1b);
        a2[i] = mishf(d2 * inv * g1c + e1c);
    }
    __syncthreads();   // all GEMM1 LDS reads done before overwrite
#pragma unroll
    for (int i = 0; i < 8; i++) {
        sT[c * PITCH + r0 + i]          = a0[i];
        sT[(c + 64) * PITCH + r0 + i]   = a1[i];
        sT[(c + 128) * PITCH + r0 + i]  = a2[i];
    }
    __syncthreads();

    // ---- GEMM2: 32 FMA per 4 weight loads, dist-2 pipeline ----
    float c0[8], c1[8], c2[8], c3[8];
#pragma unroll
    for (int i = 0; i < 8; i++) { c0[i] = 0.f; c1[i] = 0.f; c2[i] = 0.f; c3[i] = 0.f; }
    const float* w2p = w2 + c;
    float vaA = w2p[0], vbA = w2p[64], vcA = w2p[128], vdA = w2p[192];
    float vaB = w2p[HIDX], vbB = w2p[HIDX + 64], vcB = w2p[HIDX + 128], vdB = w2p[HIDX + 192];
    { const float2* p = (const float2*)&sT[r0];           xA0 = p[0]; xA1 = p[1]; xA2 = p[2]; xA3 = p[3]; }
    { const float2* p = (const float2*)&sT[PITCH + r0];   xB0 = p[0]; xB1 = p[1]; xB2 = p[2]; xB3 = p[3]; }
#pragma unroll 2
    for (int k = 0; k < VMID; k += 2) {
        int kp = (k + 2 < VMID) ? (k + 2) : k;
        float nvaA = w2p[kp * HIDX],       nvbA = w2p[kp * HIDX + 64],
              nvcA = w2p[kp * HIDX + 128], nvdA = w2p[kp * HIDX + 192];
        float nvaB = w2p[(kp + 1) * HIDX],       nvbB = w2p[(kp + 1) * HIDX + 64],
              nvcB = w2p[(kp + 1) * HIDX + 128], nvdB = w2p[(kp + 1) * HIDX + 192];
        const float2* npA = (const float2*)&sT[kp * PITCH + r0];
        const float2* npB = (const float2*)&sT[(kp + 1) * PITCH + r0];
        float2 nA0 = npA[0], nA1 = npA[1], nA2 = npA[2], nA3 = npA[3];
        float2 nB0 = npB[0], nB1 = npB[1], nB2 = npB[2], nB3 = npB[3];
        float av[8];
        av[0] = xA0.x; av[1] = xA0.y; av[2] = xA1.x; av[3] = xA1.y;
        av[4] = xA2.x; av[5] = xA2.y; av[6] = xA3.x; av[7] = xA3.y;
#pragma unroll
        for (int i = 0; i < 8; i++) {
            c0[i] += vaA * av[i]; c1[i] += vbA * av[i];
            c2[i] += vcA * av[i]; c3[i] += vdA * av[i];
        }
        av[0] = xB0.x; av[1] = xB0.y; av[2] = xB1.x; av[3] = xB1.y;
        av[4] = xB2.x; av[5] = xB2.y; av[6] = xB3.x; av[7] = xB3.y;
#pragma unroll
        for (int i = 0; i < 8; i++) {
            c0[i] += vaB * av[i]; c1[i] += vbB * av[i];
            c2[i] += vcB * av[i]; c3[i] += vdB * av[i];
        }
        vaA = nvaA; vbA = nvbA; vcA = nvcA; vdA = nvdA;
        vaB = nvaB; vbB = nvbB; vcB = nvcB; vdB = nvdB;
        xA0 = nA0; xA1 = nA1; xA2 = nA2; xA3 = nA3;
        xB0 = nB0; xB1 = nB1; xB2 = nB2; xB3 = nB3;
    }
    float b2a = b2[c], b2b = b2[c + 64], b2c = b2[c + 128], b2d = b2[c + 192];
#pragma unroll
    for (int i = 0; i < 8; i++) {
        size_t row = (size_t)(rowbase + r0 + i);
        h[row * HIDX + c]        = c0[i] + b2a;
        h[row * HIDX + c + 64]   = c1[i] + b2b;
        h[row * HIDX + c + 128]  = c2[i] + b2c;
        h[row * HIDX + c + 192]  = c3[i] + b2d;
    }
}

// fused: z (segment sum of h*keys + card) -> size MLP -> n_pred, mask, zc, worklist
__global__ __launch_bounds__(256) void k_z(const float* __restrict__ h,
    const int* __restrict__ order, const int* __restrict__ segs, const int* __restrict__ segn,
    const float* __restrict__ ct, const float* __restrict__ st,
    const float* __restrict__ cw, const float* __restrict__ cb,
    const float* __restrict__ sw1, const float* __restrict__ sb1,
    const float* __restrict__ sg, const float* __restrict__ sbe,
    const float* __restrict__ sw2, const float* __restrict__ sb2,
    float* __restrict__ zcre, float* __restrict__ zim,
    float* __restrict__ out_mask, float* __restrict__ out_np,
    int* __restrict__ wcount, int* __restrict__ wlist) {
    __shared__ float zrow[HIDX];
    __shared__ float red0[2], red1[2], red2[2];
    int b = blockIdx.x, j = threadIdx.x;
    int s = segs[b], n = segn[b];
    float zr = 0.f, zi = 0.f;
    int p = 0;
    // unroll-2: two h-rows in flight; accumulation ORDER unchanged (fp32-exact)
    for (; p + 1 < n; p += 2) {
        int e0 = order[s + p], e1 = order[s + p + 1];
        float hv0 = h[(size_t)e0 * HIDX + j];
        float hv1 = h[(size_t)e1 * HIDX + j];
        float cv0 = ct[p * HIDX + j],       sv0 = st[p * HIDX + j];
        float cv1 = ct[(p + 1) * HIDX + j], sv1 = st[(p + 1) * HIDX + j];
        zr += hv0 * cv0; zi += hv0 * sv0;
        zr += hv1 * cv1; zi += hv1 * sv1;
    }
    if (p < n) {
        int e = order[s + p];
        float hv = h[(size_t)e * HIDX + j];
        zr += hv * ct[p * HIDX + j];
        zi += hv * st[p * HIDX + j];
    }
    float nf = (float)n;
    float zrev = zr + nf * cw[j] + cb[j];
    zrow[j] = zrev;
    zim[(size_t)b * HIDX + j] = zi;
    __syncthreads();

    // size MLP (threads 0..127 active; all threads hit barriers)
    float v = 0.0f;
    if (j < SMID) {
        v = sb1[j];
        for (int k = 0; k < HIDX; k++) v += zrow[k] * sw1[k * SMID + j];
    }
    float sa = v;
#pragma unroll
    for (int off = 32; off; off >>= 1) sa += __shfl_xor(sa, off, 64);
    if (j < SMID && (j & 63) == 0) red0[j >> 6] = sa;
    __syncthreads();
    float mean = (red0[0] + red0[1]) / 128.0f;
    float d = v - mean;
    float q = d * d;
#pragma unroll
    for (int off = 32; off; off >>= 1) q += __shfl_xor(q, off, 64);
    if (j < SMID && (j & 63) == 0) red1[j >> 6] = q;
    __syncthreads();
    float var = (red1[0] + red1[1]) / 128.0f;
    float p2 = 0.0f;
    if (j < SMID) {
        float lv = d * (1.0f / sqrtf(var + 1e-5f)) * sg[j] + sbe[j];
        p2 = mishf(lv) * sw2[j];
    }
#pragma unroll
    for (int off = 32; off; off >>= 1) p2 += __shfl_xor(p2, off, 64);
    if (j < SMID && (j & 63) == 0) red2[j >> 6] = p2;
    __syncthreads();
    float h2 = red2[0] + red2[1] + sb2[0];
    float npf = fmaxf(rintf(h2), 0.0f);     // rintf == round-half-even == jnp.round
    int npi = min((int)npf, NMAXX);
    zcre[(size_t)b * HIDX + j] = zrow[j] - (npf * cw[j] + cb[j]);
    if (j < NMAXX) out_mask[b * NMAXX + j] = (j < npi) ? 1.0f : 0.0f;
    if (j == 0) {
        out_np[b] = (float)npi;
        int base = atomicAdd(wcount, npi);
        for (int m = 0; m < npi; m++) wlist[base + m] = (b << 5) | m;
    }
}

// decoder: tiled GEMM over compacted worklist, 32 items/block-tile
__global__ __launch_bounds__(256, 4) void k_dec(const float* __restrict__ zcre,
    const float* __restrict__ zim, const int* __restrict__ wcount,
    const int* __restrict__ wlist, const float* __restrict__ ct,
    const float* __restrict__ st, const float* __restrict__ w1,
    const float* __restrict__ b1, const float* __restrict__ w2,
    const float* __restrict__ b2, float* __restrict__ xr) {
    __shared__ __align__(16) float zpT[HIDX * DPITCH];  // 256x34 f32; reused as aT[192][34]
    int tid = threadIdx.x;
    int c = tid & 63;
    int r0 = (tid >> 6) * 8;
    int count = *wcount;
    int ntiles = (count + ITILE - 1) / ITILE;
    for (int tile = blockIdx.x; tile < ntiles; tile += gridDim.x) {
        int base = tile * ITILE;
        __syncthreads();   // previous tile's LDS reads complete
        // stage zp^T[k=tid][r]: zp = zc.re*cos - zc.im*sin
#pragma unroll 4
        for (int r = 0; r < ITILE; r++) {
            int item = base + r;
            float v = 0.0f;
            if (item < count) {
                int wv = wlist[item];
                int b = wv >> 5, m = wv & 31;
                v = zcre[(size_t)b * HIDX + tid] * ct[m * HIDX + tid]
                  - zim[(size_t)b * HIDX + tid] * st[m * HIDX + tid];
            }
            zpT[tid * DPITCH + r] = v;
        }
        __syncthreads();

        // GEMM1: a[item][c'] = mish(sum_k zp[item][k]*w1[k][c'] + b1), c' in {c,c+64,c+128}
        float a0[8], a1[8], a2[8];
#pragma unroll
        for (int i = 0; i < 8; i++) { a0[i] = 0.f; a1[i] = 0.f; a2[i] = 0.f; }
        const float* w1p = w1 + c;
        for (int k = 0; k < HIDX; k++) {
            float wa = w1p[k * DMID], wb = w1p[k * DMID + 64], wc = w1p[k * DMID + 128];
            const float2* zp = (const float2*)&zpT[k * DPITCH + r0];
            float zv[8];
#pragma unroll
            for (int q = 0; q < 4; q++) { float2 t2 = zp[q]; zv[2 * q] = t2.x; zv[2 * q + 1] = t2.y; }
#pragma unroll
            for (int i = 0; i < 8; i++) {
                a0[i] += wa * zv[i]; a1[i] += wb * zv[i]; a2[i] += wc * zv[i];
            }
        }
        float b1a = b1[c], b1b = b1[c + 64], b1c = b1[c + 128];
        __syncthreads();   // all GEMM1 reads done before aT overwrite
#pragma unroll
        for (int i = 0; i < 8; i++) {
            zpT[c * DPITCH + r0 + i]         = mishf(a0[i] + b1a);
            zpT[(c + 64) * DPITCH + r0 + i]  = mishf(a1[i] + b1b);
            zpT[(c + 128) * DPITCH + r0 + i] = mishf(a2[i] + b1c);
        }
        __syncthreads();

        // GEMM2: out[item][c'] = sum_k a[item][k]*w2[k][c'] + b2, c' in {c, c+64}
        float d0[8], d1[8];
#pragma unroll
        for (int i = 0; i < 8; i++) { d0[i] = 0.f; d1[i] = 0.f; }
        const float* w2p = w2 + c;
        for (int k = 0; k < DMID; k++) {
            float wa = w2p[k * DIMX], wb = w2p[k * DIMX + 64];
            const float2* ap = (const float2*)&zpT[k * DPITCH + r0];
            float av[8];
#pragma unroll
            for (int q = 0; q < 4; q++) { float2 t2 = ap[q]; av[2 * q] = t2.x; av[2 * q + 1] = t2.y; }
#pragma unroll
            for (int i = 0; i < 8; i++) { d0[i] += wa * av[i]; d1[i] += wb * av[i]; }
        }
        float b2a = b2[c], b2b = b2[c + 64];
#pragma unroll
        for (int i = 0; i < 8; i++) {
            int item = base + r0 + i;
            if (item < count) {
                int wv = wlist[item];
                int b = wv >> 5, m = wv & 31;
                size_t row = (size_t)b * NMAXX + m;
                xr[row * DIMX + c]      = d0[i] + b2a;
                xr[row * DIMX + c + 64] = d1[i] + b2b;
            }
        }
    }
}

extern "C" void kernel_launch(void* const* d_in, const int* in_sizes, int n_in,
                              void* d_out, int out_size, void* d_ws, size_t ws_size,
                              hipStream_t stream) {
    const float* x      = (const float*)d_in[0];
    const int*   batch  = (const int*)d_in[1];
    const float* rank_w = (const float*)d_in[2];
    const float* rank_b = (const float*)d_in[3];
    const float* vw1    = (const float*)d_in[4];
    const float* vb1    = (const float*)d_in[5];
    const float* vlg    = (const float*)d_in[6];
    const float* vlb    = (const float*)d_in[7];
    const float* vw2    = (const float*)d_in[8];
    const float* vb2    = (const float*)d_in[9];
    const float* cw     = (const float*)d_in[10];
    const float* cb     = (const float*)d_in[11];
    const float* sw1    = (const float*)d_in[12];
    const float* sb1    = (const float*)d_in[13];
    const float* slg    = (const float*)d_in[14];
    const float* slb    = (const float*)d_in[15];
    const float* sw2    = (const float*)d_in[16];
    const float* sb2    = (const float*)d_in[17];
    const float* dw1    = (const float*)d_in[18];
    const float* db1    = (const float*)d_in[19];
    const float* dw2    = (const float*)d_in[20];
    const float* db2    = (const float*)d_in[21];

    char* ws = (char*)d_ws;
    size_t off = 0;
    auto alloc = [&](size_t bytes) {
        void* p = ws + off;
        off += (bytes + 255) & ~(size_t)255;
        return p;
    };
    float* mag    = (float*)alloc((size_t)NTOTX * 4);
    int*   segs   = (int*)alloc((size_t)NBX * 4);
    int*   segn   = (int*)alloc((size_t)NBX * 4);
    int*   order  = (int*)alloc((size_t)NTOTX * 4);
    float* ct     = (float*)alloc((size_t)KTAB * HIDX * 4);
    float* st     = (float*)alloc((size_t)KTAB * HIDX * 4);
    float* zim    = (float*)alloc((size_t)NBX * HIDX * 4);
    float* zcre   = (float*)alloc((size_t)NBX * HIDX * 4);
    int*   wcount = (int*)alloc(256);
    int*   wlist  = (int*)alloc((size_t)NBX * NMAXX * 4);
    float* h      = (float*)alloc((size_t)NTOTX * HIDX * 4);

    float* out_xr   = (float*)d_out;
    float* out_mask = out_xr + (size_t)NBX * NMAXX * DIMX;
    float* out_np   = out_mask + (size_t)NBX * NMAXX;

    hipLaunchKernelGGL(k_prep, dim3(8449 + 2048), dim3(256), 0, stream,
                       x, rank_w, rank_b, batch, mag, segs, segn, ct, st,
                       wcount, (float4*)out_xr);
    hipLaunchKernelGGL(k_rank, dim3(NTOTX / 256), dim3(256), 0, stream,
                       batch, mag, segs, segn, order);
    hipLaunchKernelGGL(k_enc,  dim3(NTOTX / EROWS), dim3(256), 0, stream,
                       x, vw1, vb1, vlg, vlb, vw2, vb2, h);
    hipLaunchKernelGGL(k_z,    dim3(NBX), dim3(HIDX), 0, stream,
                       h, order, segs, segn, ct, st, cw, cb,
                       sw1, sb1, slg, slb, sw2, sb2,
                       zcre, zim, out_mask, out_np, wcount, wlist);
    hipLaunchKernelGGL(k_dec,  dim3(128), dim3(256), 0, stream,
                       zcre, zim, wcount, wlist, ct, st, dw1, db1, dw2, db2, out_xr);
    (void)in_sizes; (void)n_in; (void)out_size; (void)ws_size;
}

// Round 5
// 196.291 us; speedup vs baseline: 1.1437x; 1.1437x over previous
//
#include <hip/hip_runtime.h>
#include <math.h>

#define DIMX 128
#define HIDX 256
#define NBX 2048
#define NTOTX 32768
#define NMAXX 32
#define VMID 192
#define SMID 128
#define DMID 192
#define KTAB 256

#define EROWS 16
#define PITCH 18   // 16 rows + 2 pad; gcd(18,32)=2 -> 4-way write conflict max, reads broadcast

__device__ __forceinline__ float mishf(float v) {
    // exact identity: tanh(log1p(e^v)) = (u^2+2u)/(u^2+2u+2), u=e^v
    if (v > 20.0f) return v;          // tanh(softplus(v)) == 1.0f in fp32
    float u = expf(v);
    float t = u * (u + 2.0f);
    return v * (t / (t + 2.0f));
}

// fused prep: mag dot, key table, segment bounds
__global__ void k_prep(const float* __restrict__ x, const float* __restrict__ rw,
                       const float* __restrict__ rb, const int* __restrict__ batch,
                       float* __restrict__ mag, int* __restrict__ segs,
                       int* __restrict__ segn, float* __restrict__ ct,
                       float* __restrict__ st) {
    int blk = blockIdx.x, tid = threadIdx.x;
    if (blk < 8192) {                       // mag: 4 rows/block, 1 wave/row
        int gid = blk * 256 + tid;
        int row = gid >> 6, lane = gid & 63;
        const float* xr = x + (size_t)row * DIMX;
        float s = xr[lane] * rw[lane] + xr[lane + 64] * rw[lane + 64];
#pragma unroll
        for (int off = 32; off; off >>= 1) s += __shfl_down(s, off, 64);
        if (lane == 0) mag[row] = s + rb[0];
    } else if (blk < 8448) {                // key table, k = blk-8192
        int k = blk - 8192;
        float t = (float)tid * (1.0f / 255.0f);
        float th = (t * (float)k) * 8.0f;
        float sv, cv;
        sincosf(th, &sv, &cv);
        ct[k * HIDX + tid] = cv;
        st[k * HIDX + tid] = sv;
    } else {                                // segment bounds
        for (int b = tid; b < NBX; b += 256) {
            int lo = 0, hi = NTOTX;
            while (lo < hi) { int m = (lo + hi) >> 1; if (batch[m] < b) lo = m + 1; else hi = m; }
            int stt = lo;
            hi = NTOTX;
            while (lo < hi) { int m = (lo + hi) >> 1; if (batch[m] <= b) lo = m + 1; else hi = m; }
            segs[b] = stt; segn[b] = lo - stt;
        }
    }
}

// stable rank within segment -> order[]
__global__ void k_rank(const int* __restrict__ batch, const float* __restrict__ mag,
                       const int* __restrict__ segs, const int* __restrict__ segn,
                       int* __restrict__ order) {
    int i = blockIdx.x * blockDim.x + threadIdx.x;
    if (i >= NTOTX) return;
    int b = batch[i];
    int s = segs[b], e = s + segn[b];
    float mi = mag[i];
    int r = 0;
    for (int j = s; j < e; j++) {
        float mj = mag[j];
        r += (mj < mi) || (mj == mi && j < i);
    }
    order[s + r] = i;
}

// fused encoder: h = mish(LN(x@w1+b1))@w2 + b2 ; 16 rows/block, 2048 blocks,
// 13.8KB LDS + <=64 VGPR -> 8 blocks/CU = 32 waves/CU (full occupancy)
__global__ __launch_bounds__(256, 8) void k_enc(const float* __restrict__ x,
    const float* __restrict__ w1, const float* __restrict__ b1,
    const float* __restrict__ g1, const float* __restrict__ be1,
    const float* __restrict__ w2, const float* __restrict__ b2,
    float* __restrict__ h) {
    __shared__ __align__(16) float sT[VMID * PITCH];  // reused: x^T then act^T
    int tid = threadIdx.x;
    int rowbase = blockIdx.x * EROWS;

    // stage x^T: coalesced float4 reads, scattered b32 writes (one-time)
#pragma unroll
    for (int it = 0; it < 2; it++) {
        int idx = it * 256 + tid;
        int r = idx >> 5, kq = idx & 31;
        float4 v = ((const float4*)x)[(size_t)(rowbase + r) * 32 + kq];
        sT[(4 * kq + 0) * PITCH + r] = v.x;
        sT[(4 * kq + 1) * PITCH + r] = v.y;
        sT[(4 * kq + 2) * PITCH + r] = v.z;
        sT[(4 * kq + 3) * PITCH + r] = v.w;
    }
    __syncthreads();

    int c = tid & 63;      // col base (lane)
    int rg = tid >> 6;     // row group of 4
    int r0 = rg * 4;

    // ---- GEMM1: 12 FMA per 3 weight loads ----
    float a0[4], a1[4], a2[4];
#pragma unroll
    for (int i = 0; i < 4; i++) { a0[i] = 0.f; a1[i] = 0.f; a2[i] = 0.f; }
    const float* w1p = w1 + c;
#pragma unroll 4
    for (int k = 0; k < DIMX; k++) {
        float wa = w1p[k * VMID];
        float wb = w1p[k * VMID + 64];
        float wc = w1p[k * VMID + 128];
        const float2* xp = (const float2*)&sT[k * PITCH + r0];
        float2 t0 = xp[0], t1 = xp[1];
        float xv[4] = {t0.x, t0.y, t1.x, t1.y};
#pragma unroll
        for (int i = 0; i < 4; i++) {
            a0[i] += wa * xv[i];
            a1[i] += wb * xv[i];
            a2[i] += wc * xv[i];
        }
    }

    // ---- LayerNorm + mish (registers + shuffles only) ----
    float b1a = b1[c], b1b = b1[c + 64], b1c = b1[c + 128];
    float g1a = g1[c], g1b = g1[c + 64], g1c = g1[c + 128];
    float e1a = be1[c], e1b = be1[c + 64], e1c = be1[c + 128];
#pragma unroll
    for (int i = 0; i < 4; i++) {
        float v0 = a0[i] + b1a, v1 = a1[i] + b1b, v2 = a2[i] + b1c;
        float s = v0 + v1 + v2;
#pragma unroll
        for (int off = 32; off; off >>= 1) s += __shfl_xor(s, off, 64);
        float mean = s / 192.0f;
        float d0 = v0 - mean, d1 = v1 - mean, d2 = v2 - mean;
        float q = d0 * d0 + d1 * d1 + d2 * d2;
#pragma unroll
        for (int off = 32; off; off >>= 1) q += __shfl_xor(q, off, 64);
        float inv = 1.0f / sqrtf(q / 192.0f + 1e-5f);
        a0[i] = mishf(d0 * inv * g1a + e1a);
        a1[i] = mishf(d1 * inv * g1b + e1b);
        a2[i] = mishf(d2 * inv * g1c + e1c);
    }
    __syncthreads();   // all GEMM1 LDS reads done before overwrite
#pragma unroll
    for (int i = 0; i < 4; i++) {
        sT[c * PITCH + r0 + i]          = a0[i];
        sT[(c + 64) * PITCH + r0 + i]   = a1[i];
        sT[(c + 128) * PITCH + r0 + i]  = a2[i];
    }
    __syncthreads();

    // ---- GEMM2: 16 FMA per 4 weight loads ----
    float c0[4], c1[4], c2[4], c3[4];
#pragma unroll
    for (int i = 0; i < 4; i++) { c0[i] = 0.f; c1[i] = 0.f; c2[i] = 0.f; c3[i] = 0.f; }
    const float* w2p = w2 + c;
#pragma unroll 4
    for (int k = 0; k < VMID; k++) {
        float wa = w2p[k * HIDX];
        float wb = w2p[k * HIDX + 64];
        float wc = w2p[k * HIDX + 128];
        float wd = w2p[k * HIDX + 192];
        const float2* ap = (const float2*)&sT[k * PITCH + r0];
        float2 t0 = ap[0], t1 = ap[1];
        float av[4] = {t0.x, t0.y, t1.x, t1.y};
#pragma unroll
        for (int i = 0; i < 4; i++) {
            c0[i] += wa * av[i];
            c1[i] += wb * av[i];
            c2[i] += wc * av[i];
            c3[i] += wd * av[i];
        }
    }
    float b2a = b2[c], b2b = b2[c + 64], b2c = b2[c + 128], b2d = b2[c + 192];
#pragma unroll
    for (int i = 0; i < 4; i++) {
        size_t row = (size_t)(rowbase + r0 + i);
        h[row * HIDX + c]        = c0[i] + b2a;
        h[row * HIDX + c + 64]   = c1[i] + b2b;
        h[row * HIDX + c + 128]  = c2[i] + b2c;
        h[row * HIDX + c + 192]  = c3[i] + b2d;
    }
}

// fused: z (segment sum of h*keys + card) -> size MLP -> n_pred, mask, zc
__global__ __launch_bounds__(256) void k_z(const float* __restrict__ h,
    const int* __restrict__ order, const int* __restrict__ segs, const int* __restrict__ segn,
    const float* __restrict__ ct, const float* __restrict__ st,
    const float* __restrict__ cw, const float* __restrict__ cb,
    const float* __restrict__ sw1, const float* __restrict__ sb1,
    const float* __restrict__ sg, const float* __restrict__ sbe,
    const float* __restrict__ sw2, const float* __restrict__ sb2,
    float* __restrict__ zcre, float* __restrict__ zim,
    float* __restrict__ out_mask, float* __restrict__ out_np,
    int* __restrict__ npredi) {
    __shared__ float zrow[HIDX];
    __shared__ float red0[2], red1[2], red2[2];
    int b = blockIdx.x, j = threadIdx.x;
    int s = segs[b], n = segn[b];
    float zr = 0.f, zi = 0.f;
    int p = 0;
    // unroll-2: two h-rows in flight; accumulation ORDER unchanged (fp32-exact)
    for (; p + 1 < n; p += 2) {
        int e0 = order[s + p], e1 = order[s + p + 1];
        float hv0 = h[(size_t)e0 * HIDX + j];
        float hv1 = h[(size_t)e1 * HIDX + j];
        float cv0 = ct[p * HIDX + j],       sv0 = st[p * HIDX + j];
        float cv1 = ct[(p + 1) * HIDX + j], sv1 = st[(p + 1) * HIDX + j];
        zr += hv0 * cv0; zi += hv0 * sv0;
        zr += hv1 * cv1; zi += hv1 * sv1;
    }
    if (p < n) {
        int e = order[s + p];
        float hv = h[(size_t)e * HIDX + j];
        zr += hv * ct[p * HIDX + j];
        zi += hv * st[p * HIDX + j];
    }
    float nf = (float)n;
    float zrev = zr + nf * cw[j] + cb[j];
    zrow[j] = zrev;
    zim[(size_t)b * HIDX + j] = zi;
    __syncthreads();

    // size MLP (threads 0..127 active; all threads hit barriers)
    float v = 0.0f;
    if (j < SMID) {
        v = sb1[j];
        for (int k = 0; k < HIDX; k++) v += zrow[k] * sw1[k * SMID + j];
    }
    float sa = v;
#pragma unroll
    for (int off = 32; off; off >>= 1) sa += __shfl_xor(sa, off, 64);
    if (j < SMID && (j & 63) == 0) red0[j >> 6] = sa;
    __syncthreads();
    float mean = (red0[0] + red0[1]) / 128.0f;
    float d = v - mean;
    float q = d * d;
#pragma unroll
    for (int off = 32; off; off >>= 1) q += __shfl_xor(q, off, 64);
    if (j < SMID && (j & 63) == 0) red1[j >> 6] = q;
    __syncthreads();
    float var = (red1[0] + red1[1]) / 128.0f;
    float p2 = 0.0f;
    if (j < SMID) {
        float lv = d * (1.0f / sqrtf(var + 1e-5f)) * sg[j] + sbe[j];
        p2 = mishf(lv) * sw2[j];
    }
#pragma unroll
    for (int off = 32; off; off >>= 1) p2 += __shfl_xor(p2, off, 64);
    if (j < SMID && (j & 63) == 0) red2[j >> 6] = p2;
    __syncthreads();
    float h2 = red2[0] + red2[1] + sb2[0];
    float npf = fmaxf(rintf(h2), 0.0f);     // rintf == round-half-even == jnp.round
    int npi = min((int)npf, NMAXX);
    zcre[(size_t)b * HIDX + j] = zrow[j] - (npf * cw[j] + cb[j]);
    if (j < NMAXX) out_mask[b * NMAXX + j] = (j < npi) ? 1.0f : 0.0f;
    if (j == 0) { out_np[b] = (float)npi; npredi[b] = npi; }
}

// decoder: per-(m,b) blocks; masked rows write zeros (covers whole out_xr)
__global__ __launch_bounds__(256) void k_dec(const float* __restrict__ zcre,
    const float* __restrict__ zim, const int* __restrict__ npredi,
    const float* __restrict__ ct, const float* __restrict__ st,
    const float* __restrict__ w1, const float* __restrict__ b1,
    const float* __restrict__ w2, const float* __restrict__ b2,
    float* __restrict__ xr) {
    int m = blockIdx.x, b = blockIdx.y;
    int tid = threadIdx.x;
    size_t row = (size_t)b * NMAXX + m;
    if (m >= npredi[b]) {
        if (tid < DIMX) xr[row * DIMX + tid] = 0.0f;
        return;
    }
    __shared__ float zp[HIDX];
    __shared__ float a[DMID];
    {
        float cv = ct[m * HIDX + tid], sv = st[m * HIDX + tid];
        zp[tid] = zcre[(size_t)b * HIDX + tid] * cv - zim[(size_t)b * HIDX + tid] * sv;
    }
    __syncthreads();
    if (tid < DMID) {
        float v = b1[tid];
#pragma unroll 4
        for (int k = 0; k < HIDX; k++) v += zp[k] * w1[k * DMID + tid];
        a[tid] = mishf(v);
    }
    __syncthreads();
    if (tid < DIMX) {
        float v = b2[tid];
#pragma unroll 4
        for (int k = 0; k < DMID; k++) v += a[k] * w2[k * DIMX + tid];
        xr[row * DIMX + tid] = v;
    }
}

extern "C" void kernel_launch(void* const* d_in, const int* in_sizes, int n_in,
                              void* d_out, int out_size, void* d_ws, size_t ws_size,
                              hipStream_t stream) {
    const float* x      = (const float*)d_in[0];
    const int*   batch  = (const int*)d_in[1];
    const float* rank_w = (const float*)d_in[2];
    const float* rank_b = (const float*)d_in[3];
    const float* vw1    = (const float*)d_in[4];
    const float* vb1    = (const float*)d_in[5];
    const float* vlg    = (const float*)d_in[6];
    const float* vlb    = (const float*)d_in[7];
    const float* vw2    = (const float*)d_in[8];
    const float* vb2    = (const float*)d_in[9];
    const float* cw     = (const float*)d_in[10];
    const float* cb     = (const float*)d_in[11];
    const float* sw1    = (const float*)d_in[12];
    const float* sb1    = (const float*)d_in[13];
    const float* slg    = (const float*)d_in[14];
    const float* slb    = (const float*)d_in[15];
    const float* sw2    = (const float*)d_in[16];
    const float* sb2    = (const float*)d_in[17];
    const float* dw1    = (const float*)d_in[18];
    const float* db1    = (const float*)d_in[19];
    const float* dw2    = (const float*)d_in[20];
    const float* db2    = (const float*)d_in[21];

    char* ws = (char*)d_ws;
    size_t off = 0;
    auto alloc = [&](size_t bytes) {
        void* p = ws + off;
        off += (bytes + 255) & ~(size_t)255;
        return p;
    };
    float* mag    = (float*)alloc((size_t)NTOTX * 4);
    int*   segs   = (int*)alloc((size_t)NBX * 4);
    int*   segn   = (int*)alloc((size_t)NBX * 4);
    int*   order  = (int*)alloc((size_t)NTOTX * 4);
    float* ct     = (float*)alloc((size_t)KTAB * HIDX * 4);
    float* st     = (float*)alloc((size_t)KTAB * HIDX * 4);
    float* zim    = (float*)alloc((size_t)NBX * HIDX * 4);
    float* zcre   = (float*)alloc((size_t)NBX * HIDX * 4);
    int*   npi    = (int*)alloc((size_t)NBX * 4);
    float* h      = (float*)alloc((size_t)NTOTX * HIDX * 4);

    float* out_xr   = (float*)d_out;
    float* out_mask = out_xr + (size_t)NBX * NMAXX * DIMX;
    float* out_np   = out_mask + (size_t)NBX * NMAXX;

    hipLaunchKernelGGL(k_prep, dim3(8449), dim3(256), 0, stream,
                       x, rank_w, rank_b, batch, mag, segs, segn, ct, st);
    hipLaunchKernelGGL(k_rank, dim3(NTOTX / 256), dim3(256), 0, stream,
                       batch, mag, segs, segn, order);
    hipLaunchKernelGGL(k_enc,  dim3(NTOTX / EROWS), dim3(256), 0, stream,
                       x, vw1, vb1, vlg, vlb, vw2, vb2, h);
    hipLaunchKernelGGL(k_z,    dim3(NBX), dim3(HIDX), 0, stream,
                       h, order, segs, segn, ct, st, cw, cb,
                       sw1, sb1, slg, slb, sw2, sb2,
                       zcre, zim, out_mask, out_np, npi);
    hipLaunchKernelGGL(k_dec,  dim3(NMAXX, NBX), dim3(256), 0, stream,
                       zcre, zim, npi, ct, st, dw1, db1, dw2, db2, out_xr);
    (void)in_sizes; (void)n_in; (void)out_size; (void)ws_size;
}

// Round 6
// 145.321 us; speedup vs baseline: 1.5448x; 1.3507x over previous
//
#include <hip/hip_runtime.h>
#include <math.h>

#define DIMX 128
#define HIDX 256
#define NBX 2048
#define NTOTX 32768
#define NMAXX 32
#define VMID 192
#define SMID 128
#define DMID 192

#define EROWS 64
#define SPITCH 66     // [col][row] pitch: lanes r=0..63 consecutive -> conflict-free
#define NSEGMAX 128   // segment-size cap (multinomial mean 16, P(n>60) ~ 1e-16)

__device__ __forceinline__ float mishf(float v) {
    // exact identity: tanh(log1p(e^v)) = (u^2+2u)/(u^2+2u+2), u=e^v
    if (v > 20.0f) return v;          // tanh(softplus(v)) == 1.0f in fp32
    float u = expf(v);
    float t = u * (u + 2.0f);
    return v * (t / (t + 2.0f));
}

// fused encoder + mag: lane=row (64 rows), thread-group (tid>>6) = column slice.
// Weight addresses are wave-uniform -> scalar (SMEM) loads; x/act via LDS.
__global__ __launch_bounds__(512, 4) void k_enc(const float* __restrict__ x,
    const float* __restrict__ rw, const float* __restrict__ rb,
    const float* __restrict__ w1, const float* __restrict__ b1,
    const float* __restrict__ g1, const float* __restrict__ be1,
    const float* __restrict__ w2, const float* __restrict__ b2,
    float* __restrict__ h, float* __restrict__ mag) {
    __shared__ __align__(16) float sbuf[HIDX * SPITCH];  // xT[128][66] / actT[192][66] / hT[256][66]
    __shared__ float red[8 * 64];
    __shared__ float red2[8 * 64];
    int tid = threadIdx.x;
    int r = tid & 63;       // row lane
    int tg = tid >> 6;      // wave id = column group
    int rowbase = blockIdx.x * EROWS;

    // stage x^T: coalesced float4 reads
#pragma unroll
    for (int it = 0; it < 4; it++) {
        int f4 = it * 512 + tid;
        int rr = f4 >> 5, kq = f4 & 31;
        float4 v = ((const float4*)x)[(size_t)(rowbase + rr) * 32 + kq];
        sbuf[(4 * kq + 0) * SPITCH + rr] = v.x;
        sbuf[(4 * kq + 1) * SPITCH + rr] = v.y;
        sbuf[(4 * kq + 2) * SPITCH + rr] = v.z;
        sbuf[(4 * kq + 3) * SPITCH + rr] = v.w;
    }
    __syncthreads();

    // mag = x . rank_w (wave 0 only; xT stays read-only until after barrier)
    if (tid < 64) {
        float s = 0.0f;
        for (int k = 0; k < DIMX; k++) s += sbuf[k * SPITCH + tid] * rw[k];
        mag[rowbase + tid] = s + rb[0];
    }

    // ---- GEMM1: 24 cols/thread, weights scalar-loaded ----
    int cb1 = __builtin_amdgcn_readfirstlane(tg * 24);
    float acc[24];
#pragma unroll
    for (int j = 0; j < 24; j++) acc[j] = 0.0f;
#pragma unroll 2
    for (int k = 0; k < DIMX; k++) {
        float xv = sbuf[k * SPITCH + r];
        const float* wr = w1 + k * VMID + cb1;
#pragma unroll
        for (int j = 0; j < 24; j++) acc[j] += wr[j] * xv;
    }

    // ---- LayerNorm across the 8 column groups (LDS reduce) ----
    float part = 0.0f;
#pragma unroll
    for (int j = 0; j < 24; j++) { acc[j] += b1[cb1 + j]; part += acc[j]; }
    red[tg * 64 + r] = part;
    __syncthreads();
    float mean = 0.0f;
#pragma unroll
    for (int q = 0; q < 8; q++) mean += red[q * 64 + r];
    mean *= (1.0f / 192.0f);
    float vpart = 0.0f;
#pragma unroll
    for (int j = 0; j < 24; j++) { acc[j] -= mean; vpart += acc[j] * acc[j]; }
    red2[tg * 64 + r] = vpart;
    __syncthreads();
    float var = 0.0f;
#pragma unroll
    for (int q = 0; q < 8; q++) var += red2[q * 64 + r];
    var *= (1.0f / 192.0f);
    float inv = 1.0f / sqrtf(var + 1e-5f);
#pragma unroll
    for (int j = 0; j < 24; j++)
        acc[j] = mishf(acc[j] * inv * g1[cb1 + j] + be1[cb1 + j]);
    // write act^T (xT dead: all reads done before the two barriers above)
#pragma unroll
    for (int j = 0; j < 24; j++) sbuf[(cb1 + j) * SPITCH + r] = acc[j];
    __syncthreads();

    // ---- GEMM2: 32 cols/thread, weights scalar-loaded ----
    int cb2 = __builtin_amdgcn_readfirstlane(tg * 32);
    float acc2[32];
#pragma unroll
    for (int j = 0; j < 32; j++) acc2[j] = 0.0f;
#pragma unroll 2
    for (int k = 0; k < VMID; k++) {
        float av = sbuf[k * SPITCH + r];
        const float* wr = w2 + k * HIDX + cb2;
#pragma unroll
        for (int j = 0; j < 32; j++) acc2[j] += wr[j] * av;
    }
#pragma unroll
    for (int j = 0; j < 32; j++) acc2[j] += b2[cb2 + j];
    __syncthreads();      // all GEMM2 LDS reads done
#pragma unroll
    for (int j = 0; j < 32; j++) sbuf[(cb2 + j) * SPITCH + r] = acc2[j];
    __syncthreads();

    // coalesced h store via LDS transpose
#pragma unroll
    for (int it = 0; it < 8; it++) {
        int f4 = it * 512 + tid;
        int rr = f4 >> 6, cq = f4 & 63;
        float4 v;
        v.x = sbuf[(4 * cq + 0) * SPITCH + rr];
        v.y = sbuf[(4 * cq + 1) * SPITCH + rr];
        v.z = sbuf[(4 * cq + 2) * SPITCH + rr];
        v.w = sbuf[(4 * cq + 3) * SPITCH + rr];
        ((float4*)h)[(size_t)(rowbase + rr) * 64 + cq] = v;
    }
}

// fused: seg-bounds + in-LDS rank + z (segment sum, inline sincos) + size MLP
__global__ __launch_bounds__(256) void k_z(const float* __restrict__ h,
    const int* __restrict__ batch, const float* __restrict__ mag,
    const float* __restrict__ cw, const float* __restrict__ cb,
    const float* __restrict__ sw1, const float* __restrict__ sb1,
    const float* __restrict__ sg, const float* __restrict__ sbe,
    const float* __restrict__ sw2, const float* __restrict__ sb2,
    float* __restrict__ zcre, float* __restrict__ zim,
    float* __restrict__ out_mask, float* __restrict__ out_np,
    int* __restrict__ npredi) {
    __shared__ float zrow[HIDX];
    __shared__ float magL[NSEGMAX];
    __shared__ int   ordL[NSEGMAX];
    __shared__ int   shs, shn;
    __shared__ float red0[2], red1[2], red2[2];
    int b = blockIdx.x, j = threadIdx.x;
    if (j == 0) {
        int lo = 0, hi = NTOTX;
        while (lo < hi) { int m = (lo + hi) >> 1; if (batch[m] < b) lo = m + 1; else hi = m; }
        int stt = lo;
        hi = NTOTX;
        while (lo < hi) { int m = (lo + hi) >> 1; if (batch[m] <= b) lo = m + 1; else hi = m; }
        shs = stt; shn = lo - stt;
    }
    __syncthreads();
    int s = shs, n_true = shn;
    int n = (n_true < NSEGMAX) ? n_true : NSEGMAX;
    if (j < n) magL[j] = mag[s + j];
    __syncthreads();
    if (j < n) {                          // stable rank within segment (lexsort tie: idx)
        float mi = magL[j];
        int rk = 0;
        for (int q = 0; q < n; q++) {
            float mq = magL[q];
            rk += (mq < mi) || (mq == mi && q < j);
        }
        ordL[rk] = s + j;
    }
    __syncthreads();

    float t = (float)j * (1.0f / 255.0f);
    float zr = 0.f, zi = 0.f;
    int p = 0;
    for (; p + 1 < n; p += 2) {           // accumulation ORDER = p ascending (fp32-exact)
        int e0 = ordL[p], e1 = ordL[p + 1];
        float hv0 = h[(size_t)e0 * HIDX + j];
        float hv1 = h[(size_t)e1 * HIDX + j];
        float sv0, cv0, sv1, cv1;
        sincosf((t * (float)p) * 8.0f, &sv0, &cv0);
        sincosf((t * (float)(p + 1)) * 8.0f, &sv1, &cv1);
        zr += hv0 * cv0; zi += hv0 * sv0;
        zr += hv1 * cv1; zi += hv1 * sv1;
    }
    if (p < n) {
        int e = ordL[p];
        float hv = h[(size_t)e * HIDX + j];
        float sv, cv;
        sincosf((t * (float)p) * 8.0f, &sv, &cv);
        zr += hv * cv; zi += hv * sv;
    }
    float nf = (float)n_true;
    float zrev = zr + nf * cw[j] + cb[j];
    zrow[j] = zrev;
    zim[(size_t)b * HIDX + j] = zi;
    __syncthreads();

    // size MLP (threads 0..127 active; all threads hit barriers)
    float v = 0.0f;
    if (j < SMID) {
        v = sb1[j];
        for (int k = 0; k < HIDX; k++) v += zrow[k] * sw1[k * SMID + j];
    }
    float sa = v;
#pragma unroll
    for (int off = 32; off; off >>= 1) sa += __shfl_xor(sa, off, 64);
    if (j < SMID && (j & 63) == 0) red0[j >> 6] = sa;
    __syncthreads();
    float mean = (red0[0] + red0[1]) / 128.0f;
    float d = v - mean;
    float q2 = d * d;
#pragma unroll
    for (int off = 32; off; off >>= 1) q2 += __shfl_xor(q2, off, 64);
    if (j < SMID && (j & 63) == 0) red1[j >> 6] = q2;
    __syncthreads();
    float var = (red1[0] + red1[1]) / 128.0f;
    float p2 = 0.0f;
    if (j < SMID) {
        float lv = d * (1.0f / sqrtf(var + 1e-5f)) * sg[j] + sbe[j];
        p2 = mishf(lv) * sw2[j];
    }
#pragma unroll
    for (int off = 32; off; off >>= 1) p2 += __shfl_xor(p2, off, 64);
    if (j < SMID && (j & 63) == 0) red2[j >> 6] = p2;
    __syncthreads();
    float h2 = red2[0] + red2[1] + sb2[0];
    float npf = fmaxf(rintf(h2), 0.0f);     // rintf == round-half-even == jnp.round
    int npi = min((int)npf, NMAXX);
    zcre[(size_t)b * HIDX + j] = zrow[j] - (npf * cw[j] + cb[j]);
    if (j < NMAXX) out_mask[b * NMAXX + j] = (j < npi) ? 1.0f : 0.0f;
    if (j == 0) { out_np[b] = (float)npi; npredi[b] = npi; }
}

// decoder: per-(m,b) blocks; masked rows write zeros; inline sincos keys
__global__ __launch_bounds__(256) void k_dec(const float* __restrict__ zcre,
    const float* __restrict__ zim, const int* __restrict__ npredi,
    const float* __restrict__ w1, const float* __restrict__ b1,
    const float* __restrict__ w2, const float* __restrict__ b2,
    float* __restrict__ xr) {
    int m = blockIdx.x, b = blockIdx.y;
    int tid = threadIdx.x;
    size_t row = (size_t)b * NMAXX + m;
    if (m >= npredi[b]) {
        if (tid < DIMX) xr[row * DIMX + tid] = 0.0f;
        return;
    }
    __shared__ float zp[HIDX];
    __shared__ float a[DMID];
    {
        float t = (float)tid * (1.0f / 255.0f);
        float sv, cv;
        sincosf((t * (float)m) * 8.0f, &sv, &cv);
        zp[tid] = zcre[(size_t)b * HIDX + tid] * cv - zim[(size_t)b * HIDX + tid] * sv;
    }
    __syncthreads();
    if (tid < DMID) {
        float v = b1[tid];
#pragma unroll 4
        for (int k = 0; k < HIDX; k++) v += zp[k] * w1[k * DMID + tid];
        a[tid] = mishf(v);
    }
    __syncthreads();
    if (tid < DIMX) {
        float v = b2[tid];
#pragma unroll 4
        for (int k = 0; k < DMID; k++) v += a[k] * w2[k * DIMX + tid];
        xr[row * DIMX + tid] = v;
    }
}

extern "C" void kernel_launch(void* const* d_in, const int* in_sizes, int n_in,
                              void* d_out, int out_size, void* d_ws, size_t ws_size,
                              hipStream_t stream) {
    const float* x      = (const float*)d_in[0];
    const int*   batch  = (const int*)d_in[1];
    const float* rank_w = (const float*)d_in[2];
    const float* rank_b = (const float*)d_in[3];
    const float* vw1    = (const float*)d_in[4];
    const float* vb1    = (const float*)d_in[5];
    const float* vlg    = (const float*)d_in[6];
    const float* vlb    = (const float*)d_in[7];
    const float* vw2    = (const float*)d_in[8];
    const float* vb2    = (const float*)d_in[9];
    const float* cw     = (const float*)d_in[10];
    const float* cb     = (const float*)d_in[11];
    const float* sw1    = (const float*)d_in[12];
    const float* sb1    = (const float*)d_in[13];
    const float* slg    = (const float*)d_in[14];
    const float* slb    = (const float*)d_in[15];
    const float* sw2    = (const float*)d_in[16];
    const float* sb2    = (const float*)d_in[17];
    const float* dw1    = (const float*)d_in[18];
    const float* db1    = (const float*)d_in[19];
    const float* dw2    = (const float*)d_in[20];
    const float* db2    = (const float*)d_in[21];

    char* ws = (char*)d_ws;
    size_t off = 0;
    auto alloc = [&](size_t bytes) {
        void* p = ws + off;
        off += (bytes + 255) & ~(size_t)255;
        return p;
    };
    float* mag  = (float*)alloc((size_t)NTOTX * 4);
    float* zim  = (float*)alloc((size_t)NBX * HIDX * 4);
    float* zcre = (float*)alloc((size_t)NBX * HIDX * 4);
    int*   npi  = (int*)alloc((size_t)NBX * 4);
    float* h    = (float*)alloc((size_t)NTOTX * HIDX * 4);

    float* out_xr   = (float*)d_out;
    float* out_mask = out_xr + (size_t)NBX * NMAXX * DIMX;
    float* out_np   = out_mask + (size_t)NBX * NMAXX;

    hipLaunchKernelGGL(k_enc, dim3(NTOTX / EROWS), dim3(512), 0, stream,
                       x, rank_w, rank_b, vw1, vb1, vlg, vlb, vw2, vb2, h, mag);
    hipLaunchKernelGGL(k_z,   dim3(NBX), dim3(HIDX), 0, stream,
                       h, batch, mag, cw, cb,
                       sw1, sb1, slg, slb, sw2, sb2,
                       zcre, zim, out_mask, out_np, npi);
    hipLaunchKernelGGL(k_dec, dim3(NMAXX, NBX), dim3(256), 0, stream,
                       zcre, zim, npi, dw1, db1, dw2, db2, out_xr);
    (void)in_sizes; (void)n_in; (void)out_size; (void)ws_size;
}